// Round 13
// baseline (74.365 us; speedup 1.0000x reference)
//
#include <hip/hip_runtime.h>
#include <hip/hip_bf16.h>
#include <stdint.h>

static constexpr int NBATCH = 8;
static constexpr int Cin  = 64;
static constexpr int Cout = 64;
static constexpr int H = 96, W = 96;
static constexpr int HW   = H * W;            // 9216
static constexpr int NPIX = NBATCH * HW;      // 73728
static constexpr int NTILE = 48;              // pixels per tile
static constexpr int NBLK = NPIX / NTILE;     // 1536 = 3 x 512 slots exactly
static constexpr int BLK_PER_BATCH = HW / NTILE; // 192
static constexpr float EPS = 1e-5f;

typedef short    bf16x8 __attribute__((ext_vector_type(8)));
typedef float    f32x4  __attribute__((ext_vector_type(4)));
typedef uint32_t u32x4  __attribute__((ext_vector_type(4)));

__device__ inline uint16_t f2bf(float f) {
    __hip_bfloat16 h = __float2bfloat16(f);
    return *reinterpret_cast<uint16_t*>(&h);
}
__device__ inline float bf2f(uint16_t u) {
    union { uint32_t i; float f; } z;
    z.i = ((uint32_t)u) << 16;
    return z.f;
}
__device__ inline float lo_bf(uint32_t w) {
    union { uint32_t i; float f; } z; z.i = w << 16; return z.f;
}
__device__ inline float hi_bf(uint32_t w) {
    union { uint32_t i; float f; } z; z.i = w & 0xffff0000u; return z.f;
}
__device__ inline uint32_t pack_trunc(float lo, float hi) {
    union { float f; uint32_t i; } a, b;
    a.f = lo; b.f = hi;
    return (b.i & 0xffff0000u) | (a.i >> 16);
}
__device__ inline void gld_lds16(const void* g, void* l) {
    __builtin_amdgcn_global_load_lds(
        (const __attribute__((address_space(1))) void*)g,
        (__attribute__((address_space(3))) void*)l, 16, 0, 0);
}

// ---------------------------------------------------------------------------
// Kernel 1: transpose x (NCHW f32) -> xT (N,HW,C) bf16 (2 threads/pixel)
//           + weight repack (blocks 0..63) + zeropage.
// ---------------------------------------------------------------------------
__global__ __launch_bounds__(256) void transpose_pack(
        const float* __restrict__ x,
        const float* __restrict__ w_off,
        const float* __restrict__ w_def,
        uint16_t* __restrict__ xT,
        uint16_t* __restrict__ woffPack,
        uint16_t* __restrict__ wdefPack,
        float* __restrict__ zeropage) {
    int t = blockIdx.x * 256 + threadIdx.x;      // exact grid: NPIX*2 threads
    int pix  = t >> 1;
    int half = t & 1;
    int b = pix / HW, rem = pix % HW;
    const float* xb = x + (size_t)(b * Cin) * HW + rem + (size_t)(half * 32) * HW;
    uint16_t* o = xT + (size_t)pix * 64 + half * 32;
#pragma unroll
    for (int cg = 0; cg < 4; ++cg) {
        bf16x8 v;
#pragma unroll
        for (int e = 0; e < 8; ++e) v[e] = (short)f2bf(xb[(cg * 8 + e) * HW]);
        *reinterpret_cast<bf16x8*>(o + cg * 8) = v;
    }
    if (blockIdx.x < 64) {
        int t0 = blockIdx.x * 256 + threadIdx.x;
        if (t0 < 64) zeropage[t0] = 0.f;
        for (int i = t0; i < 72 * 32 * 8; i += 64 * 256) {
            int e = i & 7;
            int n = (i >> 3) & 31;
            int sg = i >> 8;
            int k = sg * 8 + e;
            int tap = k >> 6, c = k & 63;
            woffPack[i] = (n < 18) ? f2bf(w_off[(n * Cin + c) * 9 + tap]) : (uint16_t)0;
        }
        for (int i = t0; i < 72 * 64 * 8; i += 64 * 256) {
            int e = i & 7;
            int n = (i >> 3) & 63;
            int sg = i >> 9;
            int k = sg * 8 + e;
            int tap = k >> 6, c = k & 63;
            wdefPack[i] = f2bf(w_def[(n * Cin + c) * 9 + tap]);
        }
    }
}

// ---------------------------------------------------------------------------
// Kernel 2: fused deformable block — 384 threads (6 waves) / 48-pixel tile.
// Grid 1536 = exactly 3 rounds of the 512 co-resident slots (2 blocks/CU)
// -> no partial-round tail. LDS As: [tap:9][pix:48][slot:8][16B],
// slot = chunk ^ (pix&7) (involution). Phases as R11, remapped to 6 waves:
//  P1: im2col via global_load_lds (pre-swizzled src, zeropage OOB)
//  P2: offset GEMM, wave=(wj:2, kt:3); 1 B-load reused over 3 m-frags
//      -> osum[3][48][34] (alias As) -> offs[48][18]
//  P3: bilinear sampling -> As (shuffle-dedup setup, trunc pair-pack)
//  P4: deform GEMM, wave=(npair:2, kt:3); 1 B-load per 3 MFMA
//      -> red[3][48][66] (alias As) -> ybf (bf16) + BN partials
// ---------------------------------------------------------------------------
#define P3_SETUP(T, W00,W01,W10,W11,I00,I01,I10,I11)                        \
    if ((T) < 8) {                                                          \
        int src_ = lanebase + (T);                                          \
        W00 = __shfl(w00a, src_); W01 = __shfl(w01a, src_);                 \
        W10 = __shfl(w10a, src_); W11 = __shfl(w11a, src_);                 \
        I00 = __shfl(i00a, src_); I01 = __shfl(i01a, src_);                 \
        I10 = __shfl(i10a, src_); I11 = __shfl(i11a, src_);                 \
    } else {                                                                \
        W00 = w00b; W01 = w01b; W10 = w10b; W11 = w11b;                     \
        I00 = i00b; I01 = i01b; I10 = i10b; I11 = i11b;                     \
    }

#define P3_ISSUE(I00,I01,I10,I11,C00,C01,C10,C11)                           \
    C00 = *reinterpret_cast<const u32x4*>(basep + (I00) * 64);              \
    C01 = *reinterpret_cast<const u32x4*>(basep + (I01) * 64);              \
    C10 = *reinterpret_cast<const u32x4*>(basep + (I10) * 64);              \
    C11 = *reinterpret_cast<const u32x4*>(basep + (I11) * 64);

#define P3_CONV(T, W00,W01,W10,W11,C00,C01,C10,C11)                         \
    {                                                                       \
        u32x4 outv_;                                                        \
        _Pragma("unroll")                                                   \
        for (int i = 0; i < 4; ++i) {                                       \
            float slo_ = (W00) * lo_bf((C00)[i]) + (W01) * lo_bf((C01)[i])  \
                       + (W10) * lo_bf((C10)[i]) + (W11) * lo_bf((C11)[i]); \
            float shi_ = (W00) * hi_bf((C00)[i]) + (W01) * hi_bf((C01)[i])  \
                       + (W10) * hi_bf((C10)[i]) + (W11) * hi_bf((C11)[i]); \
            outv_[i] = pack_trunc(slo_, shi_);                              \
        }                                                                   \
        *reinterpret_cast<u32x4*>(&As[(((T) * NTILE + pr) * 8 + slot) * 8]) = outv_; \
    }

__global__ __launch_bounds__(384, 3) void fused_deform(
        const uint16_t* __restrict__ xT,
        const uint16_t* __restrict__ woffPack,
        const uint16_t* __restrict__ wdefPack,
        const float* __restrict__ b_off,
        const float* __restrict__ zeropage,
        uint16_t* __restrict__ ybf,
        float* __restrict__ partial) {
    __shared__ __attribute__((aligned(16))) char smem[72 * NTILE * 16]; // 55296
    __shared__ float offs[NTILE * 18];    // 3456 B
    __shared__ float s_red[128];          //  512 B
    short* As   = (short*)smem;           // bf16 im2col tile
    float* osum = (float*)smem;           // [3][48][34] alias (pre-P3)
    float* red  = (float*)smem;           // [3][48][66] alias (post-P4)

    int tid  = threadIdx.x;
    int lane = tid & 63;
    int wv   = tid >> 6;                  // 0..5
    int l15  = lane & 15;
    int lg   = lane >> 4;

    // XCD-aware swizzle: batch b -> XCD b
    int wgid  = (blockIdx.x & 7) * BLK_PER_BATCH + (blockIdx.x >> 3);
    int b     = blockIdx.x & 7;
    int rem0  = (wgid - b * BLK_PER_BATCH) * NTILE;
    const uint16_t* xTb = xT + (size_t)b * HW * 64;

    // pixel-major mapping for gather phases
    int pr   = tid >> 3;                  // local pixel 0..47
    int e8   = tid & 7;                   // channel chunk (8 ch = 16B)
    int slot = e8 ^ (pr & 7);             // LDS swizzle (involution)
    int remP = rem0 + pr;
    int hP   = remP / W, wP = remP % W;

    // ---- Phase 1: plain im2col via global_load_lds ----
    {
        const uint16_t* gsrc = xTb + slot * 8;    // pre-swizzled source chunk
        char* ldsbase = (char*)As + (size_t)wv * 1024;
#pragma unroll
        for (int tap = 0; tap < 9; ++tap) {
            int yy = hP + tap / 3 - 1;
            int xx = wP + tap % 3 - 1;
            bool ok = (yy >= 0) && (yy < H) && (xx >= 0) && (xx < W);
            const void* g = ok ? (const void*)(gsrc + (yy * W + xx) * 64)
                               : (const void*)zeropage;
            gld_lds16(g, ldsbase + tap * (NTILE * 128));
        }
    }
    __syncthreads();

    // ---- Phase 2: offset GEMM. wave = (wj = wv&1 N-frag, kt = wv>>1 K-3rd) ----
    {
        int wj = wv & 1;
        int kt = wv >> 1;                 // 0..2, s range kt*6..kt*6+5
        f32x4 oacc[3];
#pragma unroll
        for (int m = 0; m < 3; ++m) oacc[m] = (f32x4){0.f, 0.f, 0.f, 0.f};
        __builtin_amdgcn_s_setprio(1);
        for (int s = kt * 6; s < kt * 6 + 6; ++s) {
            int sg = s * 4 + lg;
            bf16x8 bb = *reinterpret_cast<const bf16x8*>(
                woffPack + (sg * 32 + wj * 16 + l15) * 8);
#pragma unroll
            for (int m = 0; m < 3; ++m) {
                bf16x8 a = *reinterpret_cast<const bf16x8*>(
                    &As[(((sg >> 3) * NTILE + m * 16 + l15) * 8 + ((sg & 7) ^ (l15 & 7))) * 8]);
                oacc[m] = __builtin_amdgcn_mfma_f32_16x16x32_bf16(a, bb, oacc[m], 0, 0, 0);
            }
        }
        __builtin_amdgcn_s_setprio(0);
        __syncthreads();     // all As reads done -> safe to alias osum over As
#pragma unroll
        for (int m = 0; m < 3; ++m)
#pragma unroll
            for (int r = 0; r < 4; ++r)
                osum[(kt * NTILE + m * 16 + lg * 4 + r) * 34 + wj * 16 + l15] = oacc[m][r];
        __syncthreads();
        for (int i = tid; i < NTILE * 18; i += 384) {
            int rr = i / 18, o = i - rr * 18;
            offs[i] = osum[rr * 34 + o] + osum[(NTILE + rr) * 34 + o]
                    + osum[(2 * NTILE + rr) * 34 + o] + b_off[o];
        }
        if (tid < 128) s_red[tid] = 0.f;
        __syncthreads();
    }

    // ---- Phase 3: bilinear sampling -> As (dedup setup + 2-deep pipeline) ----
    {
        float hm1 = (float)(hP - 1), wm1 = (float)(wP - 1);
        float w00a, w01a, w10a, w11a; int i00a, i01a, i10a, i11a;
        {
            int t = e8;
            int ty = (t * 11) >> 5;          // t/3 for t in [0,8]
            int tx = t - 3 * ty;
            float dy = offs[pr * 18 + 2 * t];
            float dx = offs[pr * 18 + 2 * t + 1];
            float py = dy + (float)ty + hm1;
            float px = dx + (float)tx + wm1;
            float y0f = floorf(py), x0f = floorf(px);
            float wy1 = py - y0f, wx1 = px - x0f;
            float wy0 = 1.f - wy1, wx0 = 1.f - wx1;
            int iy0 = (int)y0f, ix0 = (int)x0f;
            int iy1 = iy0 + 1,  ix1 = ix0 + 1;
            bool vy0 = (iy0 >= 0) && (iy0 < H), vy1 = (iy1 >= 0) && (iy1 < H);
            bool vx0 = (ix0 >= 0) && (ix0 < W), vx1 = (ix1 >= 0) && (ix1 < W);
            w00a = (vy0 && vx0) ? wy0 * wx0 : 0.f;
            w01a = (vy0 && vx1) ? wy0 * wx1 : 0.f;
            w10a = (vy1 && vx0) ? wy1 * wx0 : 0.f;
            w11a = (vy1 && vx1) ? wy1 * wx1 : 0.f;
            int cy0 = min(max(iy0, 0), H - 1), cy1 = min(max(iy1, 0), H - 1);
            int cx0 = min(max(ix0, 0), W - 1), cx1 = min(max(ix1, 0), W - 1);
            i00a = cy0 * W + cx0; i01a = cy0 * W + cx1;
            i10a = cy1 * W + cx0; i11a = cy1 * W + cx1;
        }
        float w00b, w01b, w10b, w11b; int i00b, i01b, i10b, i11b;
        {
            float dy = offs[pr * 18 + 16];
            float dx = offs[pr * 18 + 17];
            float py = dy + 2.f + hm1;
            float px = dx + 2.f + wm1;
            float y0f = floorf(py), x0f = floorf(px);
            float wy1 = py - y0f, wx1 = px - x0f;
            float wy0 = 1.f - wy1, wx0 = 1.f - wx1;
            int iy0 = (int)y0f, ix0 = (int)x0f;
            int iy1 = iy0 + 1,  ix1 = ix0 + 1;
            bool vy0 = (iy0 >= 0) && (iy0 < H), vy1 = (iy1 >= 0) && (iy1 < H);
            bool vx0 = (ix0 >= 0) && (ix0 < W), vx1 = (ix1 >= 0) && (ix1 < W);
            w00b = (vy0 && vx0) ? wy0 * wx0 : 0.f;
            w01b = (vy0 && vx1) ? wy0 * wx1 : 0.f;
            w10b = (vy1 && vx0) ? wy1 * wx0 : 0.f;
            w11b = (vy1 && vx1) ? wy1 * wx1 : 0.f;
            int cy0 = min(max(iy0, 0), H - 1), cy1 = min(max(iy1, 0), H - 1);
            int cx0 = min(max(ix0, 0), W - 1), cx1 = min(max(ix1, 0), W - 1);
            i00b = cy0 * W + cx0; i01b = cy0 * W + cx1;
            i10b = cy1 * W + cx0; i11b = cy1 * W + cx1;
        }

        const uint16_t* basep = xTb + e8 * 8;
        int lanebase = lane & 56;

        float uA0,uA1,uA2,uA3; int jA0,jA1,jA2,jA3; u32x4 cA0,cA1,cA2,cA3;
        float uB0,uB1,uB2,uB3; int jB0,jB1,jB2,jB3; u32x4 cB0,cB1,cB2,cB3;

        P3_SETUP(0, uA0,uA1,uA2,uA3, jA0,jA1,jA2,jA3)
        P3_ISSUE(jA0,jA1,jA2,jA3, cA0,cA1,cA2,cA3)
        P3_SETUP(1, uB0,uB1,uB2,uB3, jB0,jB1,jB2,jB3)
        P3_ISSUE(jB0,jB1,jB2,jB3, cB0,cB1,cB2,cB3)
        P3_CONV(0, uA0,uA1,uA2,uA3, cA0,cA1,cA2,cA3)
        P3_SETUP(2, uA0,uA1,uA2,uA3, jA0,jA1,jA2,jA3)
        P3_ISSUE(jA0,jA1,jA2,jA3, cA0,cA1,cA2,cA3)
        P3_CONV(1, uB0,uB1,uB2,uB3, cB0,cB1,cB2,cB3)
        P3_SETUP(3, uB0,uB1,uB2,uB3, jB0,jB1,jB2,jB3)
        P3_ISSUE(jB0,jB1,jB2,jB3, cB0,cB1,cB2,cB3)
        P3_CONV(2, uA0,uA1,uA2,uA3, cA0,cA1,cA2,cA3)
        P3_SETUP(4, uA0,uA1,uA2,uA3, jA0,jA1,jA2,jA3)
        P3_ISSUE(jA0,jA1,jA2,jA3, cA0,cA1,cA2,cA3)
        P3_CONV(3, uB0,uB1,uB2,uB3, cB0,cB1,cB2,cB3)
        P3_SETUP(5, uB0,uB1,uB2,uB3, jB0,jB1,jB2,jB3)
        P3_ISSUE(jB0,jB1,jB2,jB3, cB0,cB1,cB2,cB3)
        P3_CONV(4, uA0,uA1,uA2,uA3, cA0,cA1,cA2,cA3)
        P3_SETUP(6, uA0,uA1,uA2,uA3, jA0,jA1,jA2,jA3)
        P3_ISSUE(jA0,jA1,jA2,jA3, cA0,cA1,cA2,cA3)
        P3_CONV(5, uB0,uB1,uB2,uB3, cB0,cB1,cB2,cB3)
        P3_SETUP(7, uB0,uB1,uB2,uB3, jB0,jB1,jB2,jB3)
        P3_ISSUE(jB0,jB1,jB2,jB3, cB0,cB1,cB2,cB3)
        P3_CONV(6, uA0,uA1,uA2,uA3, cA0,cA1,cA2,cA3)
        P3_SETUP(8, uA0,uA1,uA2,uA3, jA0,jA1,jA2,jA3)
        P3_ISSUE(jA0,jA1,jA2,jA3, cA0,cA1,cA2,cA3)
        P3_CONV(7, uB0,uB1,uB2,uB3, cB0,cB1,cB2,cB3)
        P3_CONV(8, uA0,uA1,uA2,uA3, cA0,cA1,cA2,cA3)
    }
    __syncthreads();

    // ---- Phase 4: deform GEMM. wave = (npair = wv&1, kt = wv>>1 K-3rd) ----
    {
        int npair = wv & 1;
        int kt = wv >> 1;
        f32x4 acc[3][2];
#pragma unroll
        for (int m = 0; m < 3; ++m)
#pragma unroll
            for (int jj = 0; jj < 2; ++jj) acc[m][jj] = (f32x4){0.f, 0.f, 0.f, 0.f};
        __builtin_amdgcn_s_setprio(1);
#pragma unroll
        for (int s0 = 0; s0 < 6; ++s0) {
            int sg = (kt * 6 + s0) * 4 + lg;
#pragma unroll
            for (int jj = 0; jj < 2; ++jj) {
                int nf = npair * 2 + jj;
                bf16x8 bb = *reinterpret_cast<const bf16x8*>(
                    wdefPack + (sg * 64 + nf * 16 + l15) * 8);
#pragma unroll
                for (int m = 0; m < 3; ++m) {
                    bf16x8 a = *reinterpret_cast<const bf16x8*>(
                        &As[(((sg >> 3) * NTILE + m * 16 + l15) * 8 + ((sg & 7) ^ (l15 & 7))) * 8]);
                    acc[m][jj] = __builtin_amdgcn_mfma_f32_16x16x32_bf16(a, bb, acc[m][jj], 0, 0, 0);
                }
            }
        }
        __builtin_amdgcn_s_setprio(0);
        __syncthreads();     // all As reads done -> safe to alias red over As
#pragma unroll
        for (int m = 0; m < 3; ++m)
#pragma unroll
            for (int jj = 0; jj < 2; ++jj)
#pragma unroll
                for (int r = 0; r < 4; ++r)
                    red[(kt * NTILE + m * 16 + lg * 4 + r) * 66
                        + (npair * 2 + jj) * 16 + l15] = acc[m][jj][r];
        __syncthreads();

        // final: thread (c = tid&63, rg = tid>>6 in 0..5) -> rows rg*8..+7
        int c  = tid & 63;
        int rg = tid >> 6;
        bf16x8 ov;
        float s = 0.f, q = 0.f;
#pragma unroll
        for (int k2 = 0; k2 < 8; ++k2) {
            int r = rg * 8 + k2;
            float v = red[r * 66 + c] + red[(NTILE + r) * 66 + c]
                    + red[(2 * NTILE + r) * 66 + c];
            ov[k2] = (short)f2bf(v);
            s += v; q += v * v;
        }
        *reinterpret_cast<bf16x8*>(
            ybf + ((size_t)b * Cout + c) * HW + rem0 + rg * 8) = ov;
        atomicAdd(&s_red[c], s);
        atomicAdd(&s_red[64 + c], q);
    }
    __syncthreads();
    if (tid < 128) partial[(size_t)wgid * 128 + tid] = s_red[tid];
}

// ---------------------------------------------------------------------------
// Kernel 3a: stage-1 BN reduce: 96 blocks x 16 tiles -> partial2[96][128]
// ---------------------------------------------------------------------------
__global__ __launch_bounds__(256) void bn_reduce1(const float* __restrict__ partial,
                                                  float* __restrict__ partial2) {
    __shared__ float red[256];
    int ch = threadIdx.x & 127;
    int g  = threadIdx.x >> 7;
    float s = 0.f;
#pragma unroll
    for (int r = 0; r < 8; ++r)
        s += partial[(size_t)(blockIdx.x * 16 + g * 8 + r) * 128 + ch];
    red[threadIdx.x] = s;
    __syncthreads();
    if (g == 0)
        partial2[(size_t)blockIdx.x * 128 + ch] = red[ch] + red[128 + ch];
}

// ---------------------------------------------------------------------------
// Kernel 3b: stage-2 -> per-channel scale/shift
// ---------------------------------------------------------------------------
__global__ void bn_stats2(const float* __restrict__ partial2,
                          const float* __restrict__ gamma,
                          const float* __restrict__ beta,
                          float* __restrict__ stats) {
    __shared__ float red[256];
    int ch = threadIdx.x & 127;
    int g  = threadIdx.x >> 7;
    float s = 0.f;
    for (int i = 0; i < 48; ++i)
        s += partial2[(size_t)(g * 48 + i) * 128 + ch];
    red[threadIdx.x] = s;
    __syncthreads();
    if (threadIdx.x < 64) {
        int c = threadIdx.x;
        float sum = red[c] + red[128 + c];
        float sq  = red[64 + c] + red[192 + c];
        float mean = sum / (float)NPIX;
        float var  = sq / (float)NPIX - mean * mean;
        float v    = var + EPS;
        float inv  = rsqrtf(v);
        inv = inv * (1.5f - 0.5f * v * inv * inv);
        float sc = gamma[c] * inv;
        stats[c]      = sc;
        stats[64 + c] = beta[c] - mean * sc;
    }
}

// ---------------------------------------------------------------------------
// Kernel 4: scale/shift/ReLU: read bf16 y, write f32 out. 8 elems/thread.
// ---------------------------------------------------------------------------
__global__ __launch_bounds__(256) void bn_apply(const uint16_t* __restrict__ ybf,
                                                float* __restrict__ out,
                                                const float* __restrict__ stats) {
    int t = blockIdx.x * blockDim.x + threadIdx.x;   // exact: NPIX*64/8 threads
    int e = t * 8;
    int ch = (e / HW) & 63;
    float sc = stats[ch];
    float sh = stats[64 + ch];
    bf16x8 v = *reinterpret_cast<const bf16x8*>(ybf + e);
    f32x4 o0, o1;
#pragma unroll
    for (int i = 0; i < 4; ++i) {
        o0[i] = fmaxf(bf2f((uint16_t)v[i])     * sc + sh, 0.f);
        o1[i] = fmaxf(bf2f((uint16_t)v[4 + i]) * sc + sh, 0.f);
    }
    *reinterpret_cast<f32x4*>(out + e)     = o0;
    *reinterpret_cast<f32x4*>(out + e + 4) = o1;
}

// ---------------------------------------------------------------------------
extern "C" void kernel_launch(void* const* d_in, const int* in_sizes, int n_in,
                              void* d_out, int out_size, void* d_ws, size_t ws_size,
                              hipStream_t stream) {
    const float* x     = (const float*)d_in[0];
    const float* w_off = (const float*)d_in[1];
    const float* b_off = (const float*)d_in[2];
    const float* w_def = (const float*)d_in[3];
    // d_in[4] = b_def: constant shift, cancels exactly in BatchNorm — omitted
    const float* gamma = (const float*)d_in[5];
    const float* beta  = (const float*)d_in[6];
    float* out = (float*)d_out;
    char*  ws  = (char*)d_ws;

    // ws layout (bytes)
    uint16_t* xT       = (uint16_t*)ws;                    // 9,437,184
    uint16_t* woffPack = (uint16_t*)(ws + 9437184);        //    36,864
    uint16_t* wdefPack = (uint16_t*)(ws + 9474048);        //    73,728
    float*    partial  = (float*)(ws + 9547776);           //   786,432
    float*    partial2 = (float*)(ws + 10334208);          //    49,152
    float*    stats    = (float*)(ws + 10383360);          //       512
    float*    zeropage = (float*)(ws + 10383872);          //       256
    uint16_t* ybf      = (uint16_t*)(ws + 10384128);       // 9,437,184

    transpose_pack<<<NPIX * 2 / 256, 256, 0, stream>>>(x, w_off, w_def, xT,
                                                       woffPack, wdefPack, zeropage);
    fused_deform<<<NBLK, 384, 0, stream>>>(xT, woffPack, wdefPack, b_off,
                                           zeropage, ybf, partial);
    bn_reduce1<<<96, 256, 0, stream>>>(partial, partial2);
    bn_stats2<<<1, 256, 0, stream>>>(partial2, gamma, beta, stats);
    bn_apply<<<(NPIX * Cout / 8) / 256, 256, 0, stream>>>(ybf, out, stats);
}

// Round 14
// 57.246 us; speedup vs baseline: 1.2990x; 1.2990x over previous
//
#include <hip/hip_runtime.h>
#include <hip/hip_bf16.h>
#include <stdint.h>

static constexpr int NBATCH = 8;
static constexpr int Cin  = 64;
static constexpr int Cout = 64;
static constexpr int H = 96, W = 96;
static constexpr int HW   = H * W;          // 9216
static constexpr int NPIX = NBATCH * HW;    // 73728
static constexpr int NBLK = NPIX / 64;      // 1152
static constexpr int BLK_PER_BATCH = HW / 64; // 144
static constexpr float EPS = 1e-5f;

typedef short    bf16x8 __attribute__((ext_vector_type(8)));
typedef short    bf16x4 __attribute__((ext_vector_type(4)));
typedef float    f32x4  __attribute__((ext_vector_type(4)));
typedef uint32_t u32x4  __attribute__((ext_vector_type(4)));

__device__ inline uint16_t f2bf(float f) {
    __hip_bfloat16 h = __float2bfloat16(f);
    return *reinterpret_cast<uint16_t*>(&h);
}
__device__ inline float bf2f(uint16_t u) {
    union { uint32_t i; float f; } z;
    z.i = ((uint32_t)u) << 16;
    return z.f;
}
__device__ inline float lo_bf(uint32_t w) {
    union { uint32_t i; float f; } z; z.i = w << 16; return z.f;
}
__device__ inline float hi_bf(uint32_t w) {
    union { uint32_t i; float f; } z; z.i = w & 0xffff0000u; return z.f;
}
__device__ inline uint32_t pack_trunc(float lo, float hi) {
    union { float f; uint32_t i; } a, b;
    a.f = lo; b.f = hi;
    return (b.i & 0xffff0000u) | (a.i >> 16);
}
__device__ inline void gld_lds16(const void* g, void* l) {
    __builtin_amdgcn_global_load_lds(
        (const __attribute__((address_space(1))) void*)g,
        (__attribute__((address_space(3))) void*)l, 16, 0, 0);
}

// ---------------------------------------------------------------------------
// Kernel 1: transpose x (NCHW f32) -> xT (N,HW,C) bf16 (2 threads/pixel)
//           + weight repack (blocks 0..63) + zeropage.
// ---------------------------------------------------------------------------
__global__ __launch_bounds__(256) void transpose_pack(
        const float* __restrict__ x,
        const float* __restrict__ w_off,
        const float* __restrict__ w_def,
        uint16_t* __restrict__ xT,
        uint16_t* __restrict__ woffPack,
        uint16_t* __restrict__ wdefPack,
        float* __restrict__ zeropage) {
    int t = blockIdx.x * 256 + threadIdx.x;      // exact grid: NPIX*2 threads
    int pix  = t >> 1;
    int half = t & 1;
    int b = pix / HW, rem = pix % HW;
    const float* xb = x + (size_t)(b * Cin) * HW + rem + (size_t)(half * 32) * HW;
    uint16_t* o = xT + (size_t)pix * 64 + half * 32;
#pragma unroll
    for (int cg = 0; cg < 4; ++cg) {
        bf16x8 v;
#pragma unroll
        for (int e = 0; e < 8; ++e) v[e] = (short)f2bf(xb[(cg * 8 + e) * HW]);
        *reinterpret_cast<bf16x8*>(o + cg * 8) = v;
    }
    if (blockIdx.x < 64) {
        int t0 = blockIdx.x * 256 + threadIdx.x;
        if (t0 < 64) zeropage[t0] = 0.f;
        for (int i = t0; i < 72 * 32 * 8; i += 64 * 256) {
            int e = i & 7;
            int n = (i >> 3) & 31;
            int sg = i >> 8;
            int k = sg * 8 + e;
            int tap = k >> 6, c = k & 63;
            woffPack[i] = (n < 18) ? f2bf(w_off[(n * Cin + c) * 9 + tap]) : (uint16_t)0;
        }
        for (int i = t0; i < 72 * 64 * 8; i += 64 * 256) {
            int e = i & 7;
            int n = (i >> 3) & 63;
            int sg = i >> 9;
            int k = sg * 8 + e;
            int tap = k >> 6, c = k & 63;
            wdefPack[i] = f2bf(w_def[(n * Cin + c) * 9 + tap]);
        }
    }
}

// ---------------------------------------------------------------------------
// Kernel 2: fused deformable block, 512 thr / 64-pixel tile (R11 base).
// CHANGE vs R11: no K-split in the GEMM phases -> no osum/red LDS round
// trips, 4 barriers/tile instead of 7. Each wave owns FULL K:
//  P2: wave=(wj:2, m:4) -> oacc final -> offs written directly
//  P4: wave=(nf:4, mpair:2) -> acc final -> ybf written directly (+BN)
// LDS As: [tap:9][pix:64][slot:8][16B], slot = chunk ^ (pix&7) (involution).
// ---------------------------------------------------------------------------
#define P3_SETUP(T, W00,W01,W10,W11,I00,I01,I10,I11)                        \
    if ((T) < 8) {                                                          \
        int src_ = lanebase + (T);                                          \
        W00 = __shfl(w00a, src_); W01 = __shfl(w01a, src_);                 \
        W10 = __shfl(w10a, src_); W11 = __shfl(w11a, src_);                 \
        I00 = __shfl(i00a, src_); I01 = __shfl(i01a, src_);                 \
        I10 = __shfl(i10a, src_); I11 = __shfl(i11a, src_);                 \
    } else {                                                                \
        W00 = w00b; W01 = w01b; W10 = w10b; W11 = w11b;                     \
        I00 = i00b; I01 = i01b; I10 = i10b; I11 = i11b;                     \
    }

#define P3_ISSUE(I00,I01,I10,I11,C00,C01,C10,C11)                           \
    C00 = *reinterpret_cast<const u32x4*>(basep + (I00) * 64);              \
    C01 = *reinterpret_cast<const u32x4*>(basep + (I01) * 64);              \
    C10 = *reinterpret_cast<const u32x4*>(basep + (I10) * 64);              \
    C11 = *reinterpret_cast<const u32x4*>(basep + (I11) * 64);

#define P3_CONV(T, W00,W01,W10,W11,C00,C01,C10,C11)                         \
    {                                                                       \
        u32x4 outv_;                                                        \
        _Pragma("unroll")                                                   \
        for (int i = 0; i < 4; ++i) {                                       \
            float slo_ = (W00) * lo_bf((C00)[i]) + (W01) * lo_bf((C01)[i])  \
                       + (W10) * lo_bf((C10)[i]) + (W11) * lo_bf((C11)[i]); \
            float shi_ = (W00) * hi_bf((C00)[i]) + (W01) * hi_bf((C01)[i])  \
                       + (W10) * hi_bf((C10)[i]) + (W11) * hi_bf((C11)[i]); \
            outv_[i] = pack_trunc(slo_, shi_);                              \
        }                                                                   \
        *reinterpret_cast<u32x4*>(&As[(((T) * 64 + pr) * 8 + slot) * 8]) = outv_; \
    }

__global__ __launch_bounds__(512, 4) void fused_deform(
        const uint16_t* __restrict__ xT,
        const uint16_t* __restrict__ woffPack,
        const uint16_t* __restrict__ wdefPack,
        const float* __restrict__ b_off,
        const float* __restrict__ zeropage,
        uint16_t* __restrict__ ybf,
        float* __restrict__ partial) {
    __shared__ __attribute__((aligned(16))) char smem[73728];
    __shared__ float offs[64 * 18];       //  4608 B
    __shared__ float s_red[128];          //   512 B
    short* As = (short*)smem;             // bf16 im2col tile (only LDS user)

    int tid  = threadIdx.x;
    int lane = tid & 63;
    int wv   = tid >> 6;                  // 0..7
    int l15  = lane & 15;
    int lg   = lane >> 4;

    // XCD-aware swizzle: batch b -> XCD b
    int wgid  = (blockIdx.x & 7) * BLK_PER_BATCH + (blockIdx.x >> 3);
    int gpix0 = wgid * 64;
    int b     = gpix0 / HW;
    int rem0  = gpix0 % HW;
    const uint16_t* xTb = xT + (size_t)b * HW * 64;

    // pixel-major mapping for gather phases
    int pr   = (wv << 3) + (lane >> 3);   // local pixel 0..63
    int e8   = lane & 7;                  // channel chunk (8 ch = 16B)
    int slot = e8 ^ (pr & 7);             // LDS swizzle (= pre-swizzled src chunk)
    int remP = rem0 + pr;
    int hP   = remP / W, wP = remP % W;

    if (tid < 128) s_red[tid] = 0.f;      // covered by the P1 barrier

    // ---- Phase 1: plain im2col via global_load_lds ----
    {
        const uint16_t* gsrc = xTb + slot * 8;    // pre-swizzled source chunk
        char* ldsbase = (char*)As + (size_t)wv * 1024;
#pragma unroll
        for (int tap = 0; tap < 9; ++tap) {
            int yy = hP + tap / 3 - 1;
            int xx = wP + tap % 3 - 1;
            bool ok = (yy >= 0) && (yy < H) && (xx >= 0) && (xx < W);
            const void* g = ok ? (const void*)(gsrc + (yy * W + xx) * 64)
                               : (const void*)zeropage;
            gld_lds16(g, ldsbase + tap * 8192);
        }
    }
    __syncthreads();

    // ---- Phase 2: offset GEMM. wave = (wj = wv&1 N-frag, m = wv>>1), full K ----
    {
        int wj = wv & 1;
        int m  = wv >> 1;                 // 0..3 pixel m-frag
        f32x4 oacc = (f32x4){0.f, 0.f, 0.f, 0.f};
        __builtin_amdgcn_s_setprio(1);
#pragma unroll 6
        for (int s = 0; s < 18; ++s) {
            int sg = s * 4 + lg;
            bf16x8 bb = *reinterpret_cast<const bf16x8*>(
                woffPack + (sg * 32 + wj * 16 + l15) * 8);
            bf16x8 a = *reinterpret_cast<const bf16x8*>(
                &As[(((sg >> 3) * 64 + m * 16 + l15) * 8 + ((sg & 7) ^ (l15 & 7))) * 8]);
            oacc = __builtin_amdgcn_mfma_f32_16x16x32_bf16(a, bb, oacc, 0, 0, 0);
        }
        __builtin_amdgcn_s_setprio(0);
        // oacc is FINAL: write offs directly (o = wj*16+l15, pixels m*16+lg*4+r)
        int o = wj * 16 + l15;
        if (o < 18) {
            float bo = b_off[o];
#pragma unroll
            for (int r = 0; r < 4; ++r)
                offs[(m * 16 + lg * 4 + r) * 18 + o] = oacc[r] + bo;
        }
    }
    __syncthreads();   // offs visible + all As reads done (P3 overwrites As)

    // ---- Phase 3: bilinear sampling -> As (dedup setup + 2-deep pipeline) ----
    {
        float hm1 = (float)(hP - 1), wm1 = (float)(wP - 1);
        float w00a, w01a, w10a, w11a; int i00a, i01a, i10a, i11a;
        {
            int t = e8;
            int ty = (t * 11) >> 5;          // t/3 for t in [0,8]
            int tx = t - 3 * ty;
            float dy = offs[pr * 18 + 2 * t];
            float dx = offs[pr * 18 + 2 * t + 1];
            float py = dy + (float)ty + hm1;
            float px = dx + (float)tx + wm1;
            float y0f = floorf(py), x0f = floorf(px);
            float wy1 = py - y0f, wx1 = px - x0f;
            float wy0 = 1.f - wy1, wx0 = 1.f - wx1;
            int iy0 = (int)y0f, ix0 = (int)x0f;
            int iy1 = iy0 + 1,  ix1 = ix0 + 1;
            bool vy0 = (iy0 >= 0) && (iy0 < H), vy1 = (iy1 >= 0) && (iy1 < H);
            bool vx0 = (ix0 >= 0) && (ix0 < W), vx1 = (ix1 >= 0) && (ix1 < W);
            w00a = (vy0 && vx0) ? wy0 * wx0 : 0.f;
            w01a = (vy0 && vx1) ? wy0 * wx1 : 0.f;
            w10a = (vy1 && vx0) ? wy1 * wx0 : 0.f;
            w11a = (vy1 && vx1) ? wy1 * wx1 : 0.f;
            int cy0 = min(max(iy0, 0), H - 1), cy1 = min(max(iy1, 0), H - 1);
            int cx0 = min(max(ix0, 0), W - 1), cx1 = min(max(ix1, 0), W - 1);
            i00a = cy0 * W + cx0; i01a = cy0 * W + cx1;
            i10a = cy1 * W + cx0; i11a = cy1 * W + cx1;
        }
        float w00b, w01b, w10b, w11b; int i00b, i01b, i10b, i11b;
        {
            float dy = offs[pr * 18 + 16];
            float dx = offs[pr * 18 + 17];
            float py = dy + 2.f + hm1;
            float px = dx + 2.f + wm1;
            float y0f = floorf(py), x0f = floorf(px);
            float wy1 = py - y0f, wx1 = px - x0f;
            float wy0 = 1.f - wy1, wx0 = 1.f - wx1;
            int iy0 = (int)y0f, ix0 = (int)x0f;
            int iy1 = iy0 + 1,  ix1 = ix0 + 1;
            bool vy0 = (iy0 >= 0) && (iy0 < H), vy1 = (iy1 >= 0) && (iy1 < H);
            bool vx0 = (ix0 >= 0) && (ix0 < W), vx1 = (ix1 >= 0) && (ix1 < W);
            w00b = (vy0 && vx0) ? wy0 * wx0 : 0.f;
            w01b = (vy0 && vx1) ? wy0 * wx1 : 0.f;
            w10b = (vy1 && vx0) ? wy1 * wx0 : 0.f;
            w11b = (vy1 && vx1) ? wy1 * wx1 : 0.f;
            int cy0 = min(max(iy0, 0), H - 1), cy1 = min(max(iy1, 0), H - 1);
            int cx0 = min(max(ix0, 0), W - 1), cx1 = min(max(ix1, 0), W - 1);
            i00b = cy0 * W + cx0; i01b = cy0 * W + cx1;
            i10b = cy1 * W + cx0; i11b = cy1 * W + cx1;
        }

        const uint16_t* basep = xTb + e8 * 8;
        int lanebase = lane & 56;

        float uA0,uA1,uA2,uA3; int jA0,jA1,jA2,jA3; u32x4 cA0,cA1,cA2,cA3;
        float uB0,uB1,uB2,uB3; int jB0,jB1,jB2,jB3; u32x4 cB0,cB1,cB2,cB3;

        P3_SETUP(0, uA0,uA1,uA2,uA3, jA0,jA1,jA2,jA3)
        P3_ISSUE(jA0,jA1,jA2,jA3, cA0,cA1,cA2,cA3)
        P3_SETUP(1, uB0,uB1,uB2,uB3, jB0,jB1,jB2,jB3)
        P3_ISSUE(jB0,jB1,jB2,jB3, cB0,cB1,cB2,cB3)
        P3_CONV(0, uA0,uA1,uA2,uA3, cA0,cA1,cA2,cA3)
        P3_SETUP(2, uA0,uA1,uA2,uA3, jA0,jA1,jA2,jA3)
        P3_ISSUE(jA0,jA1,jA2,jA3, cA0,cA1,cA2,cA3)
        P3_CONV(1, uB0,uB1,uB2,uB3, cB0,cB1,cB2,cB3)
        P3_SETUP(3, uB0,uB1,uB2,uB3, jB0,jB1,jB2,jB3)
        P3_ISSUE(jB0,jB1,jB2,jB3, cB0,cB1,cB2,cB3)
        P3_CONV(2, uA0,uA1,uA2,uA3, cA0,cA1,cA2,cA3)
        P3_SETUP(4, uA0,uA1,uA2,uA3, jA0,jA1,jA2,jA3)
        P3_ISSUE(jA0,jA1,jA2,jA3, cA0,cA1,cA2,cA3)
        P3_CONV(3, uB0,uB1,uB2,uB3, cB0,cB1,cB2,cB3)
        P3_SETUP(5, uB0,uB1,uB2,uB3, jB0,jB1,jB2,jB3)
        P3_ISSUE(jB0,jB1,jB2,jB3, cB0,cB1,cB2,cB3)
        P3_CONV(4, uA0,uA1,uA2,uA3, cA0,cA1,cA2,cA3)
        P3_SETUP(6, uA0,uA1,uA2,uA3, jA0,jA1,jA2,jA3)
        P3_ISSUE(jA0,jA1,jA2,jA3, cA0,cA1,cA2,cA3)
        P3_CONV(5, uB0,uB1,uB2,uB3, cB0,cB1,cB2,cB3)
        P3_SETUP(7, uB0,uB1,uB2,uB3, jB0,jB1,jB2,jB3)
        P3_ISSUE(jB0,jB1,jB2,jB3, cB0,cB1,cB2,cB3)
        P3_CONV(6, uA0,uA1,uA2,uA3, cA0,cA1,cA2,cA3)
        P3_SETUP(8, uA0,uA1,uA2,uA3, jA0,jA1,jA2,jA3)
        P3_ISSUE(jA0,jA1,jA2,jA3, cA0,cA1,cA2,cA3)
        P3_CONV(7, uB0,uB1,uB2,uB3, cB0,cB1,cB2,cB3)
        P3_CONV(8, uA0,uA1,uA2,uA3, cA0,cA1,cA2,cA3)
    }
    __syncthreads();

    // ---- Phase 4: deform GEMM. wave = (nf = wv&3, mpair = wv>>2), full K ----
    {
        int nf = wv & 3;
        int mp = wv >> 2;                 // m-frags mp*2+{0,1}
        f32x4 acc0 = (f32x4){0.f, 0.f, 0.f, 0.f};
        f32x4 acc1 = (f32x4){0.f, 0.f, 0.f, 0.f};
        __builtin_amdgcn_s_setprio(1);
#pragma unroll 6
        for (int s = 0; s < 18; ++s) {
            int sg = s * 4 + lg;
            bf16x8 bb = *reinterpret_cast<const bf16x8*>(
                wdefPack + (sg * 64 + nf * 16 + l15) * 8);
            bf16x8 a0 = *reinterpret_cast<const bf16x8*>(
                &As[(((sg >> 3) * 64 + (mp * 2) * 16 + l15) * 8 + ((sg & 7) ^ (l15 & 7))) * 8]);
            bf16x8 a1 = *reinterpret_cast<const bf16x8*>(
                &As[(((sg >> 3) * 64 + (mp * 2 + 1) * 16 + l15) * 8 + ((sg & 7) ^ (l15 & 7))) * 8]);
            acc0 = __builtin_amdgcn_mfma_f32_16x16x32_bf16(a0, bb, acc0, 0, 0, 0);
            acc1 = __builtin_amdgcn_mfma_f32_16x16x32_bf16(a1, bb, acc1, 0, 0, 0);
        }
        __builtin_amdgcn_s_setprio(0);

        // acc final: write ybf directly + BN partials. cout = nf*16+l15,
        // pixels (mp*2+mm)*16 + lg*4 + r.
        int cout = nf * 16 + l15;
        uint16_t* yrow = ybf + ((size_t)b * Cout + cout) * HW + rem0;
        float s = 0.f, q = 0.f;
        {
            bf16x4 ov;
#pragma unroll
            for (int r = 0; r < 4; ++r) {
                float v = acc0[r];
                ov[r] = (short)f2bf(v);
                s += v; q += v * v;
            }
            *reinterpret_cast<bf16x4*>(yrow + (mp * 2) * 16 + lg * 4) = ov;
        }
        {
            bf16x4 ov;
#pragma unroll
            for (int r = 0; r < 4; ++r) {
                float v = acc1[r];
                ov[r] = (short)f2bf(v);
                s += v; q += v * v;
            }
            *reinterpret_cast<bf16x4*>(yrow + (mp * 2 + 1) * 16 + lg * 4) = ov;
        }
        // reduce over lg (lanes l15, l15+16, l15+32, l15+48), then one atomic
        s += __shfl_xor(s, 16); s += __shfl_xor(s, 32);
        q += __shfl_xor(q, 16); q += __shfl_xor(q, 32);
        if (lg == 0) {
            atomicAdd(&s_red[cout], s);
            atomicAdd(&s_red[64 + cout], q);
        }
    }
    __syncthreads();
    if (tid < 128) partial[(size_t)wgid * 128 + tid] = s_red[tid];
}

// ---------------------------------------------------------------------------
// Kernel 3a: stage-1 BN reduce: 72 blocks x 16 tiles -> partial2[72][128]
// ---------------------------------------------------------------------------
__global__ __launch_bounds__(256) void bn_reduce1(const float* __restrict__ partial,
                                                  float* __restrict__ partial2) {
    __shared__ float red[256];
    int ch = threadIdx.x & 127;
    int g  = threadIdx.x >> 7;
    float s = 0.f;
#pragma unroll
    for (int r = 0; r < 8; ++r)
        s += partial[(size_t)(blockIdx.x * 16 + g * 8 + r) * 128 + ch];
    red[threadIdx.x] = s;
    __syncthreads();
    if (g == 0)
        partial2[(size_t)blockIdx.x * 128 + ch] = red[ch] + red[128 + ch];
}

// ---------------------------------------------------------------------------
// Kernel 3b: stage-2 -> per-channel scale/shift
// ---------------------------------------------------------------------------
__global__ void bn_stats2(const float* __restrict__ partial2,
                          const float* __restrict__ gamma,
                          const float* __restrict__ beta,
                          float* __restrict__ stats) {
    __shared__ float red[256];
    int ch = threadIdx.x & 127;
    int g  = threadIdx.x >> 7;
    float s = 0.f;
    for (int i = 0; i < 36; ++i)
        s += partial2[(size_t)(g * 36 + i) * 128 + ch];
    red[threadIdx.x] = s;
    __syncthreads();
    if (threadIdx.x < 64) {
        int c = threadIdx.x;
        float sum = red[c] + red[128 + c];
        float sq  = red[64 + c] + red[192 + c];
        float mean = sum / (float)NPIX;
        float var  = sq / (float)NPIX - mean * mean;
        float v    = var + EPS;
        float inv  = rsqrtf(v);
        inv = inv * (1.5f - 0.5f * v * inv * inv);
        float sc = gamma[c] * inv;
        stats[c]      = sc;
        stats[64 + c] = beta[c] - mean * sc;
    }
}

// ---------------------------------------------------------------------------
// Kernel 4: scale/shift/ReLU: read bf16 y, write f32 out. 8 elems/thread.
// ---------------------------------------------------------------------------
__global__ __launch_bounds__(256) void bn_apply(const uint16_t* __restrict__ ybf,
                                                float* __restrict__ out,
                                                const float* __restrict__ stats) {
    int t = blockIdx.x * blockDim.x + threadIdx.x;   // exact: NPIX*64/8 threads
    int e = t * 8;
    int ch = (e / HW) & 63;
    float sc = stats[ch];
    float sh = stats[64 + ch];
    bf16x8 v = *reinterpret_cast<const bf16x8*>(ybf + e);
    f32x4 o0, o1;
#pragma unroll
    for (int i = 0; i < 4; ++i) {
        o0[i] = fmaxf(bf2f((uint16_t)v[i])     * sc + sh, 0.f);
        o1[i] = fmaxf(bf2f((uint16_t)v[4 + i]) * sc + sh, 0.f);
    }
    *reinterpret_cast<f32x4*>(out + e)     = o0;
    *reinterpret_cast<f32x4*>(out + e + 4) = o1;
}

// ---------------------------------------------------------------------------
extern "C" void kernel_launch(void* const* d_in, const int* in_sizes, int n_in,
                              void* d_out, int out_size, void* d_ws, size_t ws_size,
                              hipStream_t stream) {
    const float* x     = (const float*)d_in[0];
    const float* w_off = (const float*)d_in[1];
    const float* b_off = (const float*)d_in[2];
    const float* w_def = (const float*)d_in[3];
    // d_in[4] = b_def: constant shift, cancels exactly in BatchNorm — omitted
    const float* gamma = (const float*)d_in[5];
    const float* beta  = (const float*)d_in[6];
    float* out = (float*)d_out;
    char*  ws  = (char*)d_ws;

    // ws layout (bytes)
    uint16_t* xT       = (uint16_t*)ws;                    // 9,437,184
    uint16_t* woffPack = (uint16_t*)(ws + 9437184);        //    36,864
    uint16_t* wdefPack = (uint16_t*)(ws + 9474048);        //    73,728
    float*    partial  = (float*)(ws + 9547776);           //   589,824
    float*    partial2 = (float*)(ws + 10137600);          //    36,864
    float*    stats    = (float*)(ws + 10174464);          //       512
    float*    zeropage = (float*)(ws + 10174976);          //       256
    uint16_t* ybf      = (uint16_t*)(ws + 10175232);       // 9,437,184

    transpose_pack<<<NPIX * 2 / 256, 256, 0, stream>>>(x, w_off, w_def, xT,
                                                       woffPack, wdefPack, zeropage);
    fused_deform<<<NBLK, 512, 0, stream>>>(xT, woffPack, wdefPack, b_off,
                                           zeropage, ybf, partial);
    bn_reduce1<<<72, 256, 0, stream>>>(partial, partial2);
    bn_stats2<<<1, 256, 0, stream>>>(partial2, gamma, beta, stats);
    bn_apply<<<(NPIX * Cout / 8) / 256, 256, 0, stream>>>(ybf, out, stats);
}

// Round 15
// 55.385 us; speedup vs baseline: 1.3427x; 1.0336x over previous
//
#include <hip/hip_runtime.h>
#include <hip/hip_bf16.h>
#include <stdint.h>

static constexpr int NBATCH = 8;
static constexpr int Cin  = 64;
static constexpr int Cout = 64;
static constexpr int H = 96, W = 96;
static constexpr int HW   = H * W;          // 9216
static constexpr int NPIX = NBATCH * HW;    // 73728
static constexpr int NBLK = NPIX / 64;      // 1152
static constexpr int BLK_PER_BATCH = HW / 64; // 144
static constexpr float EPS = 1e-5f;

typedef short    bf16x8 __attribute__((ext_vector_type(8)));
typedef short    bf16x4 __attribute__((ext_vector_type(4)));
typedef float    f32x4  __attribute__((ext_vector_type(4)));
typedef uint32_t u32x4  __attribute__((ext_vector_type(4)));

__device__ inline uint16_t f2bf(float f) {
    __hip_bfloat16 h = __float2bfloat16(f);
    return *reinterpret_cast<uint16_t*>(&h);
}
__device__ inline float bf2f(uint16_t u) {
    union { uint32_t i; float f; } z;
    z.i = ((uint32_t)u) << 16;
    return z.f;
}
__device__ inline float lo_bf(uint32_t w) {
    union { uint32_t i; float f; } z; z.i = w << 16; return z.f;
}
__device__ inline float hi_bf(uint32_t w) {
    union { uint32_t i; float f; } z; z.i = w & 0xffff0000u; return z.f;
}
__device__ inline uint32_t pack_trunc(float lo, float hi) {
    union { float f; uint32_t i; } a, b;
    a.f = lo; b.f = hi;
    return (b.i & 0xffff0000u) | (a.i >> 16);
}
__device__ inline void gld_lds16(const void* g, void* l) {
    __builtin_amdgcn_global_load_lds(
        (const __attribute__((address_space(1))) void*)g,
        (__attribute__((address_space(3))) void*)l, 16, 0, 0);
}

// ---------------------------------------------------------------------------
// Kernel 1: transpose x (NCHW f32) -> xT (N,HW,C) bf16, 4 threads/pixel
//           + weight repack (blocks 0..63) + zeropage.
// ---------------------------------------------------------------------------
__global__ __launch_bounds__(256) void transpose_pack(
        const float* __restrict__ x,
        const float* __restrict__ w_off,
        const float* __restrict__ w_def,
        uint16_t* __restrict__ xT,
        uint16_t* __restrict__ woffPack,
        uint16_t* __restrict__ wdefPack,
        float* __restrict__ zeropage) {
    int t = blockIdx.x * 256 + threadIdx.x;      // exact grid: NPIX*4 threads
    int pix = t >> 2;
    int q4  = t & 3;                             // 16-channel quarter
    int b = pix / HW, rem = pix % HW;
    const float* xb = x + ((size_t)b * Cin + q4 * 16) * HW + rem;
    uint16_t* o = xT + (size_t)pix * 64 + q4 * 16;
#pragma unroll
    for (int cg = 0; cg < 2; ++cg) {
        bf16x8 v;
#pragma unroll
        for (int e = 0; e < 8; ++e) v[e] = (short)f2bf(xb[(cg * 8 + e) * HW]);
        *reinterpret_cast<bf16x8*>(o + cg * 8) = v;
    }
    if (blockIdx.x < 64) {
        int t0 = blockIdx.x * 256 + threadIdx.x;
        if (t0 < 64) zeropage[t0] = 0.f;
        for (int i = t0; i < 72 * 32 * 8; i += 64 * 256) {
            int e = i & 7;
            int n = (i >> 3) & 31;
            int sg = i >> 8;
            int k = sg * 8 + e;
            int tap = k >> 6, c = k & 63;
            woffPack[i] = (n < 18) ? f2bf(w_off[(n * Cin + c) * 9 + tap]) : (uint16_t)0;
        }
        for (int i = t0; i < 72 * 64 * 8; i += 64 * 256) {
            int e = i & 7;
            int n = (i >> 3) & 63;
            int sg = i >> 9;
            int k = sg * 8 + e;
            int tap = k >> 6, c = k & 63;
            wdefPack[i] = f2bf(w_def[(n * Cin + c) * 9 + tap]);
        }
    }
}

// ---------------------------------------------------------------------------
// Kernel 2: fused deformable block, 512 thr / 64-pixel tile (R14 base).
// CHANGE vs R14: BN partials written per-wave direct to global
// (partial[wgid*2+mp][128], lg==0 lanes, disjoint couts) -> no s_red,
// no final barrier. 3 barriers/tile total.
//  P2: wave=(wj:2, m:4) full K -> offs directly
//  P4: wave=(nf:4, mp:2) full K -> ybf directly + per-wave BN partials
// LDS As: [tap:9][pix:64][slot:8][16B], slot = chunk ^ (pix&7) (involution).
// ---------------------------------------------------------------------------
#define P3_SETUP(T, W00,W01,W10,W11,I00,I01,I10,I11)                        \
    if ((T) < 8) {                                                          \
        int src_ = lanebase + (T);                                          \
        W00 = __shfl(w00a, src_); W01 = __shfl(w01a, src_);                 \
        W10 = __shfl(w10a, src_); W11 = __shfl(w11a, src_);                 \
        I00 = __shfl(i00a, src_); I01 = __shfl(i01a, src_);                 \
        I10 = __shfl(i10a, src_); I11 = __shfl(i11a, src_);                 \
    } else {                                                                \
        W00 = w00b; W01 = w01b; W10 = w10b; W11 = w11b;                     \
        I00 = i00b; I01 = i01b; I10 = i10b; I11 = i11b;                     \
    }

#define P3_ISSUE(I00,I01,I10,I11,C00,C01,C10,C11)                           \
    C00 = *reinterpret_cast<const u32x4*>(basep + (I00) * 64);              \
    C01 = *reinterpret_cast<const u32x4*>(basep + (I01) * 64);              \
    C10 = *reinterpret_cast<const u32x4*>(basep + (I10) * 64);              \
    C11 = *reinterpret_cast<const u32x4*>(basep + (I11) * 64);

#define P3_CONV(T, W00,W01,W10,W11,C00,C01,C10,C11)                         \
    {                                                                       \
        u32x4 outv_;                                                        \
        _Pragma("unroll")                                                   \
        for (int i = 0; i < 4; ++i) {                                       \
            float slo_ = (W00) * lo_bf((C00)[i]) + (W01) * lo_bf((C01)[i])  \
                       + (W10) * lo_bf((C10)[i]) + (W11) * lo_bf((C11)[i]); \
            float shi_ = (W00) * hi_bf((C00)[i]) + (W01) * hi_bf((C01)[i])  \
                       + (W10) * hi_bf((C10)[i]) + (W11) * hi_bf((C11)[i]); \
            outv_[i] = pack_trunc(slo_, shi_);                              \
        }                                                                   \
        *reinterpret_cast<u32x4*>(&As[(((T) * 64 + pr) * 8 + slot) * 8]) = outv_; \
    }

__global__ __launch_bounds__(512, 4) void fused_deform(
        const uint16_t* __restrict__ xT,
        const uint16_t* __restrict__ woffPack,
        const uint16_t* __restrict__ wdefPack,
        const float* __restrict__ b_off,
        const float* __restrict__ zeropage,
        uint16_t* __restrict__ ybf,
        float* __restrict__ partial) {
    __shared__ __attribute__((aligned(16))) char smem[73728];
    __shared__ float offs[64 * 18];       //  4608 B
    short* As = (short*)smem;             // bf16 im2col tile (only LDS user)

    int tid  = threadIdx.x;
    int lane = tid & 63;
    int wv   = tid >> 6;                  // 0..7
    int l15  = lane & 15;
    int lg   = lane >> 4;

    // XCD-aware swizzle: batch b -> XCD b
    int wgid  = (blockIdx.x & 7) * BLK_PER_BATCH + (blockIdx.x >> 3);
    int gpix0 = wgid * 64;
    int b     = gpix0 / HW;
    int rem0  = gpix0 % HW;
    const uint16_t* xTb = xT + (size_t)b * HW * 64;

    // pixel-major mapping for gather phases
    int pr   = (wv << 3) + (lane >> 3);   // local pixel 0..63
    int e8   = lane & 7;                  // channel chunk (8 ch = 16B)
    int slot = e8 ^ (pr & 7);             // LDS swizzle (= pre-swizzled src chunk)
    int remP = rem0 + pr;
    int hP   = remP / W, wP = remP % W;

    // ---- Phase 1: plain im2col via global_load_lds ----
    {
        const uint16_t* gsrc = xTb + slot * 8;    // pre-swizzled source chunk
        char* ldsbase = (char*)As + (size_t)wv * 1024;
#pragma unroll
        for (int tap = 0; tap < 9; ++tap) {
            int yy = hP + tap / 3 - 1;
            int xx = wP + tap % 3 - 1;
            bool ok = (yy >= 0) && (yy < H) && (xx >= 0) && (xx < W);
            const void* g = ok ? (const void*)(gsrc + (yy * W + xx) * 64)
                               : (const void*)zeropage;
            gld_lds16(g, ldsbase + tap * 8192);
        }
    }
    __syncthreads();

    // ---- Phase 2: offset GEMM. wave = (wj = wv&1 N-frag, m = wv>>1), full K ----
    {
        int wj = wv & 1;
        int m  = wv >> 1;                 // 0..3 pixel m-frag
        f32x4 oacc = (f32x4){0.f, 0.f, 0.f, 0.f};
        __builtin_amdgcn_s_setprio(1);
#pragma unroll 6
        for (int s = 0; s < 18; ++s) {
            int sg = s * 4 + lg;
            bf16x8 bb = *reinterpret_cast<const bf16x8*>(
                woffPack + (sg * 32 + wj * 16 + l15) * 8);
            bf16x8 a = *reinterpret_cast<const bf16x8*>(
                &As[(((sg >> 3) * 64 + m * 16 + l15) * 8 + ((sg & 7) ^ (l15 & 7))) * 8]);
            oacc = __builtin_amdgcn_mfma_f32_16x16x32_bf16(a, bb, oacc, 0, 0, 0);
        }
        __builtin_amdgcn_s_setprio(0);
        // oacc is FINAL: write offs directly (o = wj*16+l15, pixels m*16+lg*4+r)
        int o = wj * 16 + l15;
        if (o < 18) {
            float bo = b_off[o];
#pragma unroll
            for (int r = 0; r < 4; ++r)
                offs[(m * 16 + lg * 4 + r) * 18 + o] = oacc[r] + bo;
        }
    }
    __syncthreads();   // offs visible + all As reads done (P3 overwrites As)

    // ---- Phase 3: bilinear sampling -> As (dedup setup + 2-deep pipeline) ----
    {
        float hm1 = (float)(hP - 1), wm1 = (float)(wP - 1);
        float w00a, w01a, w10a, w11a; int i00a, i01a, i10a, i11a;
        {
            int t = e8;
            int ty = (t * 11) >> 5;          // t/3 for t in [0,8]
            int tx = t - 3 * ty;
            float dy = offs[pr * 18 + 2 * t];
            float dx = offs[pr * 18 + 2 * t + 1];
            float py = dy + (float)ty + hm1;
            float px = dx + (float)tx + wm1;
            float y0f = floorf(py), x0f = floorf(px);
            float wy1 = py - y0f, wx1 = px - x0f;
            float wy0 = 1.f - wy1, wx0 = 1.f - wx1;
            int iy0 = (int)y0f, ix0 = (int)x0f;
            int iy1 = iy0 + 1,  ix1 = ix0 + 1;
            bool vy0 = (iy0 >= 0) && (iy0 < H), vy1 = (iy1 >= 0) && (iy1 < H);
            bool vx0 = (ix0 >= 0) && (ix0 < W), vx1 = (ix1 >= 0) && (ix1 < W);
            w00a = (vy0 && vx0) ? wy0 * wx0 : 0.f;
            w01a = (vy0 && vx1) ? wy0 * wx1 : 0.f;
            w10a = (vy1 && vx0) ? wy1 * wx0 : 0.f;
            w11a = (vy1 && vx1) ? wy1 * wx1 : 0.f;
            int cy0 = min(max(iy0, 0), H - 1), cy1 = min(max(iy1, 0), H - 1);
            int cx0 = min(max(ix0, 0), W - 1), cx1 = min(max(ix1, 0), W - 1);
            i00a = cy0 * W + cx0; i01a = cy0 * W + cx1;
            i10a = cy1 * W + cx0; i11a = cy1 * W + cx1;
        }
        float w00b, w01b, w10b, w11b; int i00b, i01b, i10b, i11b;
        {
            float dy = offs[pr * 18 + 16];
            float dx = offs[pr * 18 + 17];
            float py = dy + 2.f + hm1;
            float px = dx + 2.f + wm1;
            float y0f = floorf(py), x0f = floorf(px);
            float wy1 = py - y0f, wx1 = px - x0f;
            float wy0 = 1.f - wy1, wx0 = 1.f - wx1;
            int iy0 = (int)y0f, ix0 = (int)x0f;
            int iy1 = iy0 + 1,  ix1 = ix0 + 1;
            bool vy0 = (iy0 >= 0) && (iy0 < H), vy1 = (iy1 >= 0) && (iy1 < H);
            bool vx0 = (ix0 >= 0) && (ix0 < W), vx1 = (ix1 >= 0) && (ix1 < W);
            w00b = (vy0 && vx0) ? wy0 * wx0 : 0.f;
            w01b = (vy0 && vx1) ? wy0 * wx1 : 0.f;
            w10b = (vy1 && vx0) ? wy1 * wx0 : 0.f;
            w11b = (vy1 && vx1) ? wy1 * wx1 : 0.f;
            int cy0 = min(max(iy0, 0), H - 1), cy1 = min(max(iy1, 0), H - 1);
            int cx0 = min(max(ix0, 0), W - 1), cx1 = min(max(ix1, 0), W - 1);
            i00b = cy0 * W + cx0; i01b = cy0 * W + cx1;
            i10b = cy1 * W + cx0; i11b = cy1 * W + cx1;
        }

        const uint16_t* basep = xTb + e8 * 8;
        int lanebase = lane & 56;

        float uA0,uA1,uA2,uA3; int jA0,jA1,jA2,jA3; u32x4 cA0,cA1,cA2,cA3;
        float uB0,uB1,uB2,uB3; int jB0,jB1,jB2,jB3; u32x4 cB0,cB1,cB2,cB3;

        P3_SETUP(0, uA0,uA1,uA2,uA3, jA0,jA1,jA2,jA3)
        P3_ISSUE(jA0,jA1,jA2,jA3, cA0,cA1,cA2,cA3)
        P3_SETUP(1, uB0,uB1,uB2,uB3, jB0,jB1,jB2,jB3)
        P3_ISSUE(jB0,jB1,jB2,jB3, cB0,cB1,cB2,cB3)
        P3_CONV(0, uA0,uA1,uA2,uA3, cA0,cA1,cA2,cA3)
        P3_SETUP(2, uA0,uA1,uA2,uA3, jA0,jA1,jA2,jA3)
        P3_ISSUE(jA0,jA1,jA2,jA3, cA0,cA1,cA2,cA3)
        P3_CONV(1, uB0,uB1,uB2,uB3, cB0,cB1,cB2,cB3)
        P3_SETUP(3, uB0,uB1,uB2,uB3, jB0,jB1,jB2,jB3)
        P3_ISSUE(jB0,jB1,jB2,jB3, cB0,cB1,cB2,cB3)
        P3_CONV(2, uA0,uA1,uA2,uA3, cA0,cA1,cA2,cA3)
        P3_SETUP(4, uA0,uA1,uA2,uA3, jA0,jA1,jA2,jA3)
        P3_ISSUE(jA0,jA1,jA2,jA3, cA0,cA1,cA2,cA3)
        P3_CONV(3, uB0,uB1,uB2,uB3, cB0,cB1,cB2,cB3)
        P3_SETUP(5, uB0,uB1,uB2,uB3, jB0,jB1,jB2,jB3)
        P3_ISSUE(jB0,jB1,jB2,jB3, cB0,cB1,cB2,cB3)
        P3_CONV(4, uA0,uA1,uA2,uA3, cA0,cA1,cA2,cA3)
        P3_SETUP(6, uA0,uA1,uA2,uA3, jA0,jA1,jA2,jA3)
        P3_ISSUE(jA0,jA1,jA2,jA3, cA0,cA1,cA2,cA3)
        P3_CONV(5, uB0,uB1,uB2,uB3, cB0,cB1,cB2,cB3)
        P3_SETUP(7, uB0,uB1,uB2,uB3, jB0,jB1,jB2,jB3)
        P3_ISSUE(jB0,jB1,jB2,jB3, cB0,cB1,cB2,cB3)
        P3_CONV(6, uA0,uA1,uA2,uA3, cA0,cA1,cA2,cA3)
        P3_SETUP(8, uA0,uA1,uA2,uA3, jA0,jA1,jA2,jA3)
        P3_ISSUE(jA0,jA1,jA2,jA3, cA0,cA1,cA2,cA3)
        P3_CONV(7, uB0,uB1,uB2,uB3, cB0,cB1,cB2,cB3)
        P3_CONV(8, uA0,uA1,uA2,uA3, cA0,cA1,cA2,cA3)
    }
    __syncthreads();

    // ---- Phase 4: deform GEMM. wave = (nf = wv&3, mp = wv>>2), full K ----
    {
        int nf = wv & 3;
        int mp = wv >> 2;                 // m-frags mp*2+{0,1}
        f32x4 acc0 = (f32x4){0.f, 0.f, 0.f, 0.f};
        f32x4 acc1 = (f32x4){0.f, 0.f, 0.f, 0.f};
        __builtin_amdgcn_s_setprio(1);
#pragma unroll 6
        for (int s = 0; s < 18; ++s) {
            int sg = s * 4 + lg;
            bf16x8 bb = *reinterpret_cast<const bf16x8*>(
                wdefPack + (sg * 64 + nf * 16 + l15) * 8);
            bf16x8 a0 = *reinterpret_cast<const bf16x8*>(
                &As[(((sg >> 3) * 64 + (mp * 2) * 16 + l15) * 8 + ((sg & 7) ^ (l15 & 7))) * 8]);
            bf16x8 a1 = *reinterpret_cast<const bf16x8*>(
                &As[(((sg >> 3) * 64 + (mp * 2 + 1) * 16 + l15) * 8 + ((sg & 7) ^ (l15 & 7))) * 8]);
            acc0 = __builtin_amdgcn_mfma_f32_16x16x32_bf16(a0, bb, acc0, 0, 0, 0);
            acc1 = __builtin_amdgcn_mfma_f32_16x16x32_bf16(a1, bb, acc1, 0, 0, 0);
        }
        __builtin_amdgcn_s_setprio(0);

        // acc final: write ybf + per-wave BN partials (no LDS, no barrier)
        int cout = nf * 16 + l15;
        uint16_t* yrow = ybf + ((size_t)b * Cout + cout) * HW + rem0;
        float s = 0.f, q = 0.f;
        {
            bf16x4 ov;
#pragma unroll
            for (int r = 0; r < 4; ++r) {
                float v = acc0[r];
                ov[r] = (short)f2bf(v);
                s += v; q += v * v;
            }
            *reinterpret_cast<bf16x4*>(yrow + (mp * 2) * 16 + lg * 4) = ov;
        }
        {
            bf16x4 ov;
#pragma unroll
            for (int r = 0; r < 4; ++r) {
                float v = acc1[r];
                ov[r] = (short)f2bf(v);
                s += v; q += v * v;
            }
            *reinterpret_cast<bf16x4*>(yrow + (mp * 2 + 1) * 16 + lg * 4) = ov;
        }
        // reduce over lg (lanes l15, +16, +32, +48); lg==0 writes global
        s += __shfl_xor(s, 16); s += __shfl_xor(s, 32);
        q += __shfl_xor(q, 16); q += __shfl_xor(q, 32);
        if (lg == 0) {
            float* prow = partial + ((size_t)wgid * 2 + mp) * 128;
            prow[cout]      = s;
            prow[64 + cout] = q;
        }
    }
}

// ---------------------------------------------------------------------------
// Kernel 3a: stage-1 BN reduce: 72 blocks x 32 rows -> partial2[72][128]
// ---------------------------------------------------------------------------
__global__ __launch_bounds__(256) void bn_reduce1(const float* __restrict__ partial,
                                                  float* __restrict__ partial2) {
    __shared__ float red[256];
    int ch = threadIdx.x & 127;
    int g  = threadIdx.x >> 7;
    float s = 0.f;
#pragma unroll
    for (int r = 0; r < 16; ++r)
        s += partial[(size_t)(blockIdx.x * 32 + g * 16 + r) * 128 + ch];
    red[threadIdx.x] = s;
    __syncthreads();
    if (g == 0)
        partial2[(size_t)blockIdx.x * 128 + ch] = red[ch] + red[128 + ch];
}

// ---------------------------------------------------------------------------
// Kernel 3b: stage-2 -> per-channel scale/shift
// ---------------------------------------------------------------------------
__global__ void bn_stats2(const float* __restrict__ partial2,
                          const float* __restrict__ gamma,
                          const float* __restrict__ beta,
                          float* __restrict__ stats) {
    __shared__ float red[256];
    int ch = threadIdx.x & 127;
    int g  = threadIdx.x >> 7;
    float s = 0.f;
    for (int i = 0; i < 36; ++i)
        s += partial2[(size_t)(g * 36 + i) * 128 + ch];
    red[threadIdx.x] = s;
    __syncthreads();
    if (threadIdx.x < 64) {
        int c = threadIdx.x;
        float sum = red[c] + red[128 + c];
        float sq  = red[64 + c] + red[192 + c];
        float mean = sum / (float)NPIX;
        float var  = sq / (float)NPIX - mean * mean;
        float v    = var + EPS;
        float inv  = rsqrtf(v);
        inv = inv * (1.5f - 0.5f * v * inv * inv);
        float sc = gamma[c] * inv;
        stats[c]      = sc;
        stats[64 + c] = beta[c] - mean * sc;
    }
}

// ---------------------------------------------------------------------------
// Kernel 4: scale/shift/ReLU: read bf16 y, write f32 out. 8 elems/thread.
// ---------------------------------------------------------------------------
__global__ __launch_bounds__(256) void bn_apply(const uint16_t* __restrict__ ybf,
                                                float* __restrict__ out,
                                                const float* __restrict__ stats) {
    int t = blockIdx.x * blockDim.x + threadIdx.x;   // exact: NPIX*64/8 threads
    int e = t * 8;
    int ch = (e / HW) & 63;
    float sc = stats[ch];
    float sh = stats[64 + ch];
    bf16x8 v = *reinterpret_cast<const bf16x8*>(ybf + e);
    f32x4 o0, o1;
#pragma unroll
    for (int i = 0; i < 4; ++i) {
        o0[i] = fmaxf(bf2f((uint16_t)v[i])     * sc + sh, 0.f);
        o1[i] = fmaxf(bf2f((uint16_t)v[4 + i]) * sc + sh, 0.f);
    }
    *reinterpret_cast<f32x4*>(out + e)     = o0;
    *reinterpret_cast<f32x4*>(out + e + 4) = o1;
}

// ---------------------------------------------------------------------------
extern "C" void kernel_launch(void* const* d_in, const int* in_sizes, int n_in,
                              void* d_out, int out_size, void* d_ws, size_t ws_size,
                              hipStream_t stream) {
    const float* x     = (const float*)d_in[0];
    const float* w_off = (const float*)d_in[1];
    const float* b_off = (const float*)d_in[2];
    const float* w_def = (const float*)d_in[3];
    // d_in[4] = b_def: constant shift, cancels exactly in BatchNorm — omitted
    const float* gamma = (const float*)d_in[5];
    const float* beta  = (const float*)d_in[6];
    float* out = (float*)d_out;
    char*  ws  = (char*)d_ws;

    // ws layout (bytes)
    uint16_t* xT       = (uint16_t*)ws;                    // 9,437,184
    uint16_t* woffPack = (uint16_t*)(ws + 9437184);        //    36,864
    uint16_t* wdefPack = (uint16_t*)(ws + 9474048);        //    73,728
    float*    partial  = (float*)(ws + 9547776);           // 1,179,648
    float*    partial2 = (float*)(ws + 10727424);          //    36,864
    float*    stats    = (float*)(ws + 10764288);          //       512
    float*    zeropage = (float*)(ws + 10764800);          //       256
    uint16_t* ybf      = (uint16_t*)(ws + 10765056);       // 9,437,184

    transpose_pack<<<NPIX * 4 / 256, 256, 0, stream>>>(x, w_off, w_def, xT,
                                                       woffPack, wdefPack, zeropage);
    fused_deform<<<NBLK, 512, 0, stream>>>(xT, woffPack, wdefPack, b_off,
                                           zeropage, ybf, partial);
    bn_reduce1<<<72, 256, 0, stream>>>(partial, partial2);
    bn_stats2<<<1, 256, 0, stream>>>(partial2, gamma, beta, stats);
    bn_apply<<<(NPIX * Cout / 8) / 256, 256, 0, stream>>>(ybf, out, stats);
}